// Round 1
// baseline (735.660 us; speedup 1.0000x reference)
//
#include <hip/hip_runtime.h>

#define NB   4
#define SEQ  2048
#define CH   512
#define NH   8
#define HD   64
#define C3   1536

// ---------------------------------------------------------------------------
// GEMM1: qkv = x @ W_in   (x: [8192,512], W_in: [512,1536])
// Epilogue scatters each 64-col tile (exactly one (t,h) slice) into
// q/k/v buffers laid out [B][H][N][D] for the attention kernel.
// Tiling: BM=64, BN=64, BK=16, 256 threads, 4x4 micro-tile / thread.
// ---------------------------------------------------------------------------
__global__ __launch_bounds__(256) void gemm_qkv(const float* __restrict__ x,
                                                const float* __restrict__ Win,
                                                float* __restrict__ qb,
                                                float* __restrict__ kb,
                                                float* __restrict__ vb) {
  __shared__ float As[16][68];  // stored transposed: As[k][m]
  __shared__ float Bs[16][68];  // Bs[k][n]
  const int t  = threadIdx.x;
  const int m0 = blockIdx.y * 64;
  const int n0 = blockIdx.x * 64;
  const int tm = t >> 4, tn = t & 15;
  float acc[4][4] = {};

  for (int k0 = 0; k0 < CH; k0 += 16) {
    {
      const float4 a = *reinterpret_cast<const float4*>(
          &x[(size_t)(m0 + (t >> 2)) * CH + k0 + (t & 3) * 4]);
      const int kk = (t & 3) * 4, mm = t >> 2;
      As[kk + 0][mm] = a.x; As[kk + 1][mm] = a.y;
      As[kk + 2][mm] = a.z; As[kk + 3][mm] = a.w;
    }
    {
      const float4 b = *reinterpret_cast<const float4*>(
          &Win[(size_t)(k0 + (t >> 4)) * C3 + n0 + (t & 15) * 4]);
      *reinterpret_cast<float4*>(&Bs[t >> 4][(t & 15) * 4]) = b;
    }
    __syncthreads();
#pragma unroll
    for (int k = 0; k < 16; ++k) {
      float a[4], b[4];
      *(float4*)a = *(float4*)&As[k][tm * 4];
      *(float4*)b = *(float4*)&Bs[k][tn * 4];
#pragma unroll
      for (int i = 0; i < 4; ++i)
#pragma unroll
        for (int j = 0; j < 4; ++j)
          acc[i][j] = fmaf(a[i], b[j], acc[i][j]);
    }
    __syncthreads();
  }

  // scatter: this block's 64 cols are exactly one (t,h) slice
  const int tq = n0 >> 9;            // 0=q 1=k 2=v
  const int h  = (n0 >> 6) & 7;
  float* dst = (tq == 0) ? qb : ((tq == 1) ? kb : vb);
  const int b   = m0 >> 11;
  const int n0r = m0 & (SEQ - 1);
  float* base = dst + ((size_t)(b * NH + h) * SEQ) * HD;
#pragma unroll
  for (int i = 0; i < 4; ++i) {
    const int n = n0r + tm * 4 + i;
    float4 v4 = make_float4(acc[i][0], acc[i][1], acc[i][2], acc[i][3]);
    *reinterpret_cast<float4*>(&base[(size_t)n * HD + tn * 4]) = v4;
  }
}

// ---------------------------------------------------------------------------
// Flash-style attention, fp32. One block per (b*h, 64 q-rows).
// K and V time-share one LDS buffer (keeps static LDS < 64 KB).
// ---------------------------------------------------------------------------
__global__ __launch_bounds__(256) void attn_fwd(const float* __restrict__ q,
                                                const float* __restrict__ k,
                                                const float* __restrict__ v,
                                                float* __restrict__ ao) {
  __shared__ float QsT[64][68];   // QsT[d][r], pre-scaled
  __shared__ float KVs[64][68];   // phase A: K^T as KVs[d][c]; phase C: V as KVs[c][d]
  __shared__ float Ss[64][68];    // scores / probabilities
  __shared__ float mrow[64], lrow[64], resc[64];

  const int t  = threadIdx.x;
  const int bh = blockIdx.y;
  const int q0 = blockIdx.x * 64;
  const float scale = 0.125f;     // 1/sqrt(64)
  const float* qp = q + (size_t)bh * SEQ * HD;
  const float* kp = k + (size_t)bh * SEQ * HD;
  const float* vp = v + (size_t)bh * SEQ * HD;

  // load Q tile transposed + pre-scaled
#pragma unroll
  for (int c = 0; c < 4; ++c) {
    const int idx = c * 1024 + t * 4;
    const int r = idx >> 6, col = idx & 63;
    float4 qv = *reinterpret_cast<const float4*>(&qp[(size_t)(q0 + r) * HD + col]);
    QsT[col + 0][r] = qv.x * scale;
    QsT[col + 1][r] = qv.y * scale;
    QsT[col + 2][r] = qv.z * scale;
    QsT[col + 3][r] = qv.w * scale;
  }
  if (t < 64) { mrow[t] = -__builtin_inff(); lrow[t] = 0.f; }

  const int r4 = t >> 4, c4 = t & 15;
  float o[4][4] = {};

  for (int kt = 0; kt < SEQ; kt += 64) {
    __syncthreads();  // prev phase C done before K overwrites KVs
    // load K transposed
#pragma unroll
    for (int c = 0; c < 4; ++c) {
      const int idx = c * 1024 + t * 4;
      const int r = idx >> 6, col = idx & 63;
      float4 kv = *reinterpret_cast<const float4*>(&kp[(size_t)(kt + r) * HD + col]);
      KVs[col + 0][r] = kv.x; KVs[col + 1][r] = kv.y;
      KVs[col + 2][r] = kv.z; KVs[col + 3][r] = kv.w;
    }
    __syncthreads();
    // phase A: S = (Q*scale) K^T
    {
      float acc[4][4] = {};
      for (int dd = 0; dd < 64; ++dd) {
        float a[4], b[4];
        *(float4*)a = *(float4*)&QsT[dd][r4 * 4];
        *(float4*)b = *(float4*)&KVs[dd][c4 * 4];
#pragma unroll
        for (int i = 0; i < 4; ++i)
#pragma unroll
          for (int j = 0; j < 4; ++j)
            acc[i][j] = fmaf(a[i], b[j], acc[i][j]);
      }
#pragma unroll
      for (int i = 0; i < 4; ++i)
        *(float4*)&Ss[r4 * 4 + i][c4 * 4] = *(float4*)&acc[i][0];
    }
    __syncthreads();  // Ss written, KVs free for V
    // phase B: online softmax update (4 lanes per row) — overlapped with V load
    {
      const int row = t >> 2, cq = (t & 3) * 16;
      float4 sv[4];
#pragma unroll
      for (int u = 0; u < 4; ++u) sv[u] = *(float4*)&Ss[row][cq + u * 4];
      float mx = -__builtin_inff();
#pragma unroll
      for (int u = 0; u < 4; ++u)
        mx = fmaxf(mx, fmaxf(fmaxf(sv[u].x, sv[u].y), fmaxf(sv[u].z, sv[u].w)));
      mx = fmaxf(mx, __shfl_xor(mx, 1));
      mx = fmaxf(mx, __shfl_xor(mx, 2));
      const float mold = mrow[row];
      const float mnew = fmaxf(mold, mx);
      float sum = 0.f;
#pragma unroll
      for (int u = 0; u < 4; ++u) {
        sv[u].x = __expf(sv[u].x - mnew); sv[u].y = __expf(sv[u].y - mnew);
        sv[u].z = __expf(sv[u].z - mnew); sv[u].w = __expf(sv[u].w - mnew);
        sum += sv[u].x + sv[u].y + sv[u].z + sv[u].w;
        *(float4*)&Ss[row][cq + u * 4] = sv[u];
      }
      sum += __shfl_xor(sum, 1);
      sum += __shfl_xor(sum, 2);
      if ((t & 3) == 0) {
        const float r = __expf(mold - mnew);   // first tile: exp(-inf)=0
        lrow[row] = lrow[row] * r + sum;
        mrow[row] = mnew;
        resc[row] = r;
      }
      // load V (row-major) into KVs — safe: only Ss/m/l touched above
#pragma unroll
      for (int c = 0; c < 4; ++c) {
        const int idx = c * 1024 + t * 4;
        const int r = idx >> 6, col = idx & 63;
        float4 vv = *reinterpret_cast<const float4*>(&vp[(size_t)(kt + r) * HD + col]);
        *reinterpret_cast<float4*>(&KVs[r][col]) = vv;
      }
    }
    __syncthreads();
    // phase C: O = resc*O + P @ V
    {
      float rs[4];
#pragma unroll
      for (int i = 0; i < 4; ++i) rs[i] = resc[r4 * 4 + i];
#pragma unroll
      for (int i = 0; i < 4; ++i)
#pragma unroll
        for (int j = 0; j < 4; ++j) o[i][j] *= rs[i];
      for (int c = 0; c < 64; ++c) {
        float s[4], vv[4];
#pragma unroll
        for (int i = 0; i < 4; ++i) s[i] = Ss[r4 * 4 + i][c];
        *(float4*)vv = *(float4*)&KVs[c][c4 * 4];
#pragma unroll
        for (int i = 0; i < 4; ++i)
#pragma unroll
          for (int j = 0; j < 4; ++j)
            o[i][j] = fmaf(s[i], vv[j], o[i][j]);
      }
    }
  }

  // epilogue: normalize, write [b][n][h*64+d] (row-major [8192][512])
  const int b = bh >> 3, h = bh & 7;
#pragma unroll
  for (int i = 0; i < 4; ++i) {
    const float inv = 1.f / lrow[r4 * 4 + i];
    const int n = q0 + r4 * 4 + i;
    float4 o4 = make_float4(o[i][0] * inv, o[i][1] * inv, o[i][2] * inv, o[i][3] * inv);
    *reinterpret_cast<float4*>(&ao[((size_t)(b * SEQ + n)) * CH + h * HD + c4 * 4]) = o4;
  }
}

// ---------------------------------------------------------------------------
// GEMM2: out = attn_out @ W_out + b_out   ([8192,512] @ [512,512])
// ---------------------------------------------------------------------------
__global__ __launch_bounds__(256) void gemm_out(const float* __restrict__ A,
                                                const float* __restrict__ W,
                                                const float* __restrict__ bias,
                                                float* __restrict__ out) {
  __shared__ float As[16][68];
  __shared__ float Bs[16][68];
  const int t  = threadIdx.x;
  const int m0 = blockIdx.y * 64;
  const int n0 = blockIdx.x * 64;
  const int tm = t >> 4, tn = t & 15;
  float acc[4][4] = {};

  for (int k0 = 0; k0 < CH; k0 += 16) {
    {
      const float4 a = *reinterpret_cast<const float4*>(
          &A[(size_t)(m0 + (t >> 2)) * CH + k0 + (t & 3) * 4]);
      const int kk = (t & 3) * 4, mm = t >> 2;
      As[kk + 0][mm] = a.x; As[kk + 1][mm] = a.y;
      As[kk + 2][mm] = a.z; As[kk + 3][mm] = a.w;
    }
    {
      const float4 b = *reinterpret_cast<const float4*>(
          &W[(size_t)(k0 + (t >> 4)) * CH + n0 + (t & 15) * 4]);
      *reinterpret_cast<float4*>(&Bs[t >> 4][(t & 15) * 4]) = b;
    }
    __syncthreads();
#pragma unroll
    for (int k = 0; k < 16; ++k) {
      float a[4], b[4];
      *(float4*)a = *(float4*)&As[k][tm * 4];
      *(float4*)b = *(float4*)&Bs[k][tn * 4];
#pragma unroll
      for (int i = 0; i < 4; ++i)
#pragma unroll
        for (int j = 0; j < 4; ++j)
          acc[i][j] = fmaf(a[i], b[j], acc[i][j]);
    }
    __syncthreads();
  }

  const float4 bv = *reinterpret_cast<const float4*>(&bias[n0 + tn * 4]);
#pragma unroll
  for (int i = 0; i < 4; ++i) {
    const int m = m0 + tm * 4 + i;
    float4 o4 = make_float4(acc[i][0] + bv.x, acc[i][1] + bv.y,
                            acc[i][2] + bv.z, acc[i][3] + bv.w);
    *reinterpret_cast<float4*>(&out[(size_t)m * CH + n0 + tn * 4]) = o4;
  }
}

// ---------------------------------------------------------------------------
extern "C" void kernel_launch(void* const* d_in, const int* in_sizes, int n_in,
                              void* d_out, int out_size, void* d_ws, size_t ws_size,
                              hipStream_t stream) {
  const float* x    = (const float*)d_in[0];
  const float* Win  = (const float*)d_in[1];
  const float* Wout = (const float*)d_in[2];
  const float* bout = (const float*)d_in[3];
  float* out = (float*)d_out;
  float* ws  = (float*)d_ws;

  // ws layout (floats): q[4M] k[4M] v[4M] attn_out[4M] = 64 MiB total
  float* qb = ws;
  float* kb = ws + (size_t)4 * 1024 * 1024;
  float* vb = ws + (size_t)8 * 1024 * 1024;
  float* ao = ws + (size_t)12 * 1024 * 1024;

  dim3 g1(C3 / 64, (NB * SEQ) / 64);   // 24 x 128
  gemm_qkv<<<g1, 256, 0, stream>>>(x, Win, qb, kb, vb);

  dim3 g2(SEQ / 64, NB * NH);          // 32 x 32
  attn_fwd<<<g2, 256, 0, stream>>>(qb, kb, vb, ao);

  dim3 g3(CH / 64, (NB * SEQ) / 64);   // 8 x 128
  gemm_out<<<g3, 256, 0, stream>>>(ao, Wout, bout, out);
}

// Round 2
// 171.357 us; speedup vs baseline: 4.2931x; 4.2931x over previous
//
#include <hip/hip_runtime.h>

typedef unsigned short u16;
typedef unsigned int   u32;
using s16x8 = __attribute__((ext_vector_type(8))) short;
using f32x4 = __attribute__((ext_vector_type(4))) float;

#define NB   4
#define SEQ  2048
#define CH   512
#define NH   8
#define HD   64
#define C3   1536

__device__ __forceinline__ u16 f2bf(float f) {
  u32 u = __float_as_uint(f);
  u32 r = u + 0x7fffu + ((u >> 16) & 1u);
  return (u16)(r >> 16);
}

// async global->LDS, 16B per lane. LDS dest must be wave-uniform-base + lane*16.
#define GLL16(gp, lp) __builtin_amdgcn_global_load_lds( \
    (const __attribute__((address_space(1))) u32*)(gp), \
    (__attribute__((address_space(3))) u32*)(lp), 16, 0, 0)

// ---------------------------------------------------------------------------
// convert x -> bf16 (packed)
// ---------------------------------------------------------------------------
__global__ __launch_bounds__(256) void conv_x(const float* __restrict__ in,
                                              u16* __restrict__ out, int n4) {
  int i = blockIdx.x * 256 + threadIdx.x;
  if (i >= n4) return;
  float4 v = ((const float4*)in)[i];
  u32 a = (u32)f2bf(v.x) | ((u32)f2bf(v.y) << 16);
  u32 b = (u32)f2bf(v.z) | ((u32)f2bf(v.w) << 16);
  ((uint2*)out)[i] = make_uint2(a, b);
}

// ---------------------------------------------------------------------------
// convert + transpose: in [R][C] fp32 -> out [C][R] bf16 (64x64 tiles)
// ---------------------------------------------------------------------------
__global__ __launch_bounds__(256) void conv_tr(const float* __restrict__ in,
                                               u16* __restrict__ out, int R, int C) {
  __shared__ float tb[64][68];
  const int c0 = blockIdx.x * 64, r0 = blockIdx.y * 64;
  const int t = threadIdx.x;
#pragma unroll
  for (int i = 0; i < 4; ++i) {
    int idx = i * 1024 + t * 4;
    int r = idx >> 6, c = idx & 63;
    float4 v = *(const float4*)(&in[(size_t)(r0 + r) * C + c0 + c]);
    tb[r][c] = v.x; tb[r][c + 1] = v.y; tb[r][c + 2] = v.z; tb[r][c + 3] = v.w;
  }
  __syncthreads();
  const int cc = t >> 2, rr0 = (t & 3) * 16;
  u16 tmp[16];
#pragma unroll
  for (int j = 0; j < 16; ++j) tmp[j] = f2bf(tb[rr0 + j][cc]);
#pragma unroll
  for (int j = 0; j < 4; ++j) {
    u32 a = (u32)tmp[4 * j] | ((u32)tmp[4 * j + 1] << 16);
    u32 b = (u32)tmp[4 * j + 2] | ((u32)tmp[4 * j + 3] << 16);
    *(uint2*)(&out[(size_t)(c0 + cc) * R + r0 + rr0 + 4 * j]) = make_uint2(a, b);
  }
}

// ---------------------------------------------------------------------------
// shared bf16 MFMA GEMM core: C[128x128] tile, BK=64, A[M][K] row-major bf16,
// B given as BT[N][K] row-major bf16. Both row strides = 512 elems (1024 B).
// LDS XOR-swizzled (pre-swizzled global source, swizzled frag reads).
// ---------------------------------------------------------------------------
template <int KTOT>
__device__ __forceinline__ void gemm_core(const u16* __restrict__ Ag,
                                          const u16* __restrict__ Bg,
                                          int m0, int n0, f32x4 (&acc)[4][4],
                                          u16* As, u16* Bs) {
  const int t = threadIdx.x;
  const int l = t & 63, w = t >> 6;
  const int wr = w >> 1, wc = w & 1;
  const int lo = l & 15, hi = l >> 4;
  const int srow_base = w * 8 + (l >> 3);
  const int scolb = (l & 7) * 16;

  for (int k0 = 0; k0 < KTOT; k0 += 64) {
    __syncthreads();
#pragma unroll
    for (int i = 0; i < 4; ++i) {
      int row = i * 32 + srow_base;
      int sw  = (row & 7) << 4;
      GLL16((const char*)Ag + (size_t)(m0 + row) * 1024 + k0 * 2 + (scolb ^ sw),
            (char*)As + row * 128 + scolb);
      GLL16((const char*)Bg + (size_t)(n0 + row) * 1024 + k0 * 2 + (scolb ^ sw),
            (char*)Bs + row * 128 + scolb);
    }
    __syncthreads();
#pragma unroll
    for (int s = 0; s < 2; ++s) {
      s16x8 af[4], bf[4];
#pragma unroll
      for (int mi = 0; mi < 4; ++mi) {
        int row = wr * 64 + mi * 16 + lo;
        af[mi] = *(const s16x8*)((const char*)As + row * 128 +
                                 ((s * 64 + hi * 16) ^ ((row & 7) << 4)));
      }
#pragma unroll
      for (int ni = 0; ni < 4; ++ni) {
        int row = wc * 64 + ni * 16 + lo;
        bf[ni] = *(const s16x8*)((const char*)Bs + row * 128 +
                                 ((s * 64 + hi * 16) ^ ((row & 7) << 4)));
      }
#pragma unroll
      for (int mi = 0; mi < 4; ++mi)
#pragma unroll
        for (int ni = 0; ni < 4; ++ni)
          acc[mi][ni] = __builtin_amdgcn_mfma_f32_16x16x32_bf16(af[mi], bf[ni],
                                                                acc[mi][ni], 0, 0, 0);
    }
  }
}

// ---------------------------------------------------------------------------
// GEMM1: qkv = x @ W_in, scatter to q/k/v [B][H][N][D] bf16; q pre-scaled 1/8
// ---------------------------------------------------------------------------
__global__ __launch_bounds__(256) void gemm_qkv(const u16* __restrict__ xb,
                                                const u16* __restrict__ WinT,
                                                u16* __restrict__ qb,
                                                u16* __restrict__ kb,
                                                u16* __restrict__ vb) {
  __shared__ __align__(16) u16 As[8192];
  __shared__ __align__(16) u16 Bs[8192];
  const int m0 = blockIdx.y * 128, n0 = blockIdx.x * 128;
  f32x4 acc[4][4];
#pragma unroll
  for (int i = 0; i < 4; ++i)
#pragma unroll
    for (int j = 0; j < 4; ++j) acc[i][j] = (f32x4){0.f, 0.f, 0.f, 0.f};

  gemm_core<CH>(xb, WinT, m0, n0, acc, As, Bs);

  const int t = threadIdx.x, l = t & 63, w = t >> 6;
  const int wr = w >> 1, wc = w & 1, lo = l & 15, hi = l >> 4;
#pragma unroll
  for (int ni = 0; ni < 4; ++ni) {
    const int n = n0 + wc * 64 + ni * 16 + lo;
    const int tq = n >> 9, h = (n >> 6) & 7, d = n & 63;
    u16* dst = (tq == 0) ? qb : ((tq == 1) ? kb : vb);
    const float sc = (tq == 0) ? 0.125f : 1.0f;
#pragma unroll
    for (int mi = 0; mi < 4; ++mi)
#pragma unroll
      for (int r = 0; r < 4; ++r) {
        const int m = m0 + wr * 64 + mi * 16 + hi * 4 + r;
        const int b = m >> 11, ns = m & (SEQ - 1);
        dst[((size_t)((b * NH + h) * SEQ + ns)) * HD + d] = f2bf(acc[mi][ni][r] * sc);
      }
  }
}

// ---------------------------------------------------------------------------
// MFMA flash attention: block = (b,h) x 64 q-rows, 4 waves x 16 rows.
// ---------------------------------------------------------------------------
__global__ __launch_bounds__(256) void attn(const u16* __restrict__ qg,
                                            const u16* __restrict__ kg,
                                            const u16* __restrict__ vg,
                                            u16* __restrict__ ao) {
  __shared__ __align__(16) u16 Ks[4096];   // [64 kv][64 d] swizzled
  __shared__ __align__(16) u16 Vs[4096];   // VT [64 d][64 kv] swizzled
  __shared__ __align__(16) u16 Ps[4096];   // 4 waves x [16 q][64 kv] swizzled
  const int t = threadIdx.x, l = t & 63, w = t >> 6;
  const int lo = l & 15, hi = l >> 4;
  const int bh = blockIdx.y, q0 = blockIdx.x * 64;
  const u16* qp = qg + (size_t)bh * SEQ * HD;
  const u16* kp = kg + (size_t)bh * SEQ * HD;
  const u16* vp = vg + (size_t)bh * SEQ * HD;

  s16x8 qf[2];
#pragma unroll
  for (int s = 0; s < 2; ++s)
    qf[s] = *(const s16x8*)(qp + (size_t)(q0 + w * 16 + lo) * HD + s * 32 + hi * 8);

  f32x4 oacc[4];
#pragma unroll
  for (int i = 0; i < 4; ++i) oacc[i] = (f32x4){0.f, 0.f, 0.f, 0.f};
  float m_r[4], l_r[4];
#pragma unroll
  for (int r = 0; r < 4; ++r) { m_r[r] = -1e30f; l_r[r] = 0.f; }

  const int vkv = (t & 31) * 2, vd0 = (t >> 5) * 8;
  u16* Pw = Ps + w * 1024;

  for (int kt = 0; kt < SEQ; kt += 64) {
    __syncthreads();
    // stage K (async, swizzled source)
#pragma unroll
    for (int i = 0; i < 2; ++i) {
      int o = i * 4096 + t * 16;
      int row = o >> 7, colb = o & 127;
      GLL16((const char*)kp + (size_t)(kt + row) * 128 + (colb ^ ((row & 7) << 4)),
            (char*)Ks + o);
    }
    // stage V transposed: VT[d][kv], packed pair writes
    {
      s16x8 v0 = *(const s16x8*)(vp + (size_t)(kt + vkv) * HD + vd0);
      s16x8 v1 = *(const s16x8*)(vp + (size_t)(kt + vkv + 1) * HD + vd0);
#pragma unroll
      for (int j = 0; j < 8; ++j) {
        int d = vd0 + j;
        u32 pw = (u32)(u16)v0[j] | ((u32)(u16)v1[j] << 16);
        *(u32*)((char*)Vs + ((d * 128 + vkv * 2) ^ ((d & 7) << 4))) = pw;
      }
    }
    __syncthreads();
    // QK^T: S[16 q][64 kv] per wave (q pre-scaled)
    f32x4 sacc[4];
#pragma unroll
    for (int i = 0; i < 4; ++i) sacc[i] = (f32x4){0.f, 0.f, 0.f, 0.f};
#pragma unroll
    for (int s = 0; s < 2; ++s)
#pragma unroll
      for (int ct = 0; ct < 4; ++ct) {
        int row = ct * 16 + lo;
        s16x8 kf = *(const s16x8*)((const char*)Ks + row * 128 +
                                   ((s * 64 + hi * 16) ^ ((row & 7) << 4)));
        sacc[ct] = __builtin_amdgcn_mfma_f32_16x16x32_bf16(qf[s], kf, sacc[ct], 0, 0, 0);
      }
    // online softmax in registers (rows are lane-local in C-layout)
    float resc[4];
#pragma unroll
    for (int r = 0; r < 4; ++r) {
      float mx = fmaxf(fmaxf(sacc[0][r], sacc[1][r]), fmaxf(sacc[2][r], sacc[3][r]));
#pragma unroll
      for (int off = 1; off < 16; off <<= 1) mx = fmaxf(mx, __shfl_xor(mx, off));
      float mn = fmaxf(m_r[r], mx);
      resc[r] = __expf(m_r[r] - mn);
      m_r[r] = mn;
      float ps = 0.f;
#pragma unroll
      for (int ct = 0; ct < 4; ++ct) {
        float p = __expf(sacc[ct][r] - mn);
        sacc[ct][r] = p;
        ps += p;
      }
#pragma unroll
      for (int off = 1; off < 16; off <<= 1) ps += __shfl_xor(ps, off);
      l_r[r] = l_r[r] * resc[r] + ps;
    }
    // write P (bf16, swizzled), rescale O
#pragma unroll
    for (int r = 0; r < 4; ++r) {
      const int prow = hi * 4 + r;
      const int rb = prow * 128, sw = (prow & 7) << 4;
#pragma unroll
      for (int ct = 0; ct < 4; ++ct)
        *(u16*)((char*)Pw + ((rb + (ct * 16 + lo) * 2) ^ sw)) = f2bf(sacc[ct][r]);
#pragma unroll
      for (int ct = 0; ct < 4; ++ct) oacc[ct][r] *= resc[r];
    }
    __syncthreads();
    // PV: O += P @ V
    s16x8 pa[2];
#pragma unroll
    for (int s = 0; s < 2; ++s)
      pa[s] = *(const s16x8*)((const char*)Pw + lo * 128 +
                              ((s * 64 + hi * 16) ^ ((lo & 7) << 4)));
#pragma unroll
    for (int s = 0; s < 2; ++s)
#pragma unroll
      for (int ct = 0; ct < 4; ++ct) {
        int row = ct * 16 + lo;
        s16x8 vf = *(const s16x8*)((const char*)Vs + row * 128 +
                                   ((s * 64 + hi * 16) ^ ((row & 7) << 4)));
        oacc[ct] = __builtin_amdgcn_mfma_f32_16x16x32_bf16(pa[s], vf, oacc[ct], 0, 0, 0);
      }
  }
  // epilogue -> ao [B][N][C] bf16
  const int b = bh >> 3, h = bh & 7;
#pragma unroll
  for (int r = 0; r < 4; ++r) {
    const float inv = 1.0f / l_r[r];
    const int q = q0 + w * 16 + hi * 4 + r;
    const size_t base = ((size_t)(b * SEQ) + q) * CH + h * HD;
#pragma unroll
    for (int ct = 0; ct < 4; ++ct)
      ao[base + ct * 16 + lo] = f2bf(oacc[ct][r] * inv);
  }
}

// ---------------------------------------------------------------------------
// GEMM2: out = ao @ W_out + b_out (fp32 out)
// ---------------------------------------------------------------------------
__global__ __launch_bounds__(256) void gemm_out(const u16* __restrict__ ao,
                                                const u16* __restrict__ WoutT,
                                                const float* __restrict__ bias,
                                                float* __restrict__ out) {
  __shared__ __align__(16) u16 As[8192];
  __shared__ __align__(16) u16 Bs[8192];
  const int m0 = blockIdx.y * 128, n0 = blockIdx.x * 128;
  f32x4 acc[4][4];
#pragma unroll
  for (int i = 0; i < 4; ++i)
#pragma unroll
    for (int j = 0; j < 4; ++j) acc[i][j] = (f32x4){0.f, 0.f, 0.f, 0.f};

  gemm_core<CH>(ao, WoutT, m0, n0, acc, As, Bs);

  const int t = threadIdx.x, l = t & 63, w = t >> 6;
  const int wr = w >> 1, wc = w & 1, lo = l & 15, hi = l >> 4;
#pragma unroll
  for (int ni = 0; ni < 4; ++ni) {
    const int n = n0 + wc * 64 + ni * 16 + lo;
    const float bv = bias[n];
#pragma unroll
    for (int mi = 0; mi < 4; ++mi)
#pragma unroll
      for (int r = 0; r < 4; ++r) {
        const int m = m0 + wr * 64 + mi * 16 + hi * 4 + r;
        out[(size_t)m * CH + n] = acc[mi][ni][r] + bv;
      }
  }
}

// ---------------------------------------------------------------------------
extern "C" void kernel_launch(void* const* d_in, const int* in_sizes, int n_in,
                              void* d_out, int out_size, void* d_ws, size_t ws_size,
                              hipStream_t stream) {
  const float* x    = (const float*)d_in[0];
  const float* Win  = (const float*)d_in[1];
  const float* Wout = (const float*)d_in[2];
  const float* bout = (const float*)d_in[3];
  float* out = (float*)d_out;
  char* ws = (char*)d_ws;

  const size_t MB = 1u << 20;
  u16* xb    = (u16*)(ws);             // 8 MB  [8192][512]
  u16* WinT  = (u16*)(ws + 8 * MB);    // 1.5MB [1536][512]
  u16* WoutT = (u16*)(ws + 10 * MB);   // 0.5MB [512][512]
  u16* qb    = (u16*)(ws + 12 * MB);   // 8 MB  [B][H][N][D]
  u16* kb    = (u16*)(ws + 20 * MB);
  u16* vb    = (u16*)(ws + 28 * MB);
  u16* ao    = (u16*)(ws + 36 * MB);   // 8 MB  [8192][512]

  conv_x<<<4096, 256, 0, stream>>>(x, xb, (NB * SEQ * CH) / 4);
  conv_tr<<<dim3(C3 / 64, CH / 64), 256, 0, stream>>>(Win, WinT, CH, C3);
  conv_tr<<<dim3(CH / 64, CH / 64), 256, 0, stream>>>(Wout, WoutT, CH, CH);

  gemm_qkv<<<dim3(C3 / 128, (NB * SEQ) / 128), 256, 0, stream>>>(xb, WinT, qb, kb, vb);
  attn<<<dim3(SEQ / 64, NB * NH), 256, 0, stream>>>(qb, kb, vb, ao);
  gemm_out<<<dim3(CH / 128, (NB * SEQ) / 128), 256, 0, stream>>>(ao, WoutT, bout, out);
}

// Round 3
// 119.016 us; speedup vs baseline: 6.1812x; 1.4398x over previous
//
#include <hip/hip_runtime.h>

typedef unsigned short u16;
typedef unsigned int   u32;
using s16x8 = __attribute__((ext_vector_type(8))) short;
using s16x4 = __attribute__((ext_vector_type(4))) short;
using f32x4 = __attribute__((ext_vector_type(4))) float;

#define NB   4
#define SEQ  2048
#define CH   512
#define NH   8
#define HD   64
#define C3   1536
#define LOG2E 1.44269504088896f

__device__ __forceinline__ u16 f2bf(float f) {
  u32 u = __float_as_uint(f);
  u32 r = u + 0x7fffu + ((u >> 16) & 1u);
  return (u16)(r >> 16);
}

__device__ __forceinline__ u32 cvtpk(float a, float b) {
  u32 r;
  asm("v_cvt_pk_bf16_f32 %0, %1, %2" : "=v"(r) : "v"(a), "v"(b));
  return r;
}

__device__ __forceinline__ float ex2(float x) {
#if __has_builtin(__builtin_amdgcn_exp2f)
  return __builtin_amdgcn_exp2f(x);
#else
  return exp2f(x);
#endif
}

// async global->LDS, 16B per lane. LDS dest must be wave-uniform-base + lane*16.
#define GLL16(gp, lp) __builtin_amdgcn_global_load_lds( \
    (const __attribute__((address_space(1))) u32*)(gp), \
    (__attribute__((address_space(3))) u32*)(lp), 16, 0, 0)

// ---------------------------------------------------------------------------
// convert x -> bf16 (packed)
// ---------------------------------------------------------------------------
__global__ __launch_bounds__(256) void conv_x(const float* __restrict__ in,
                                              u16* __restrict__ out, int n4) {
  int i = blockIdx.x * 256 + threadIdx.x;
  if (i >= n4) return;
  float4 v = ((const float4*)in)[i];
  u32 a = (u32)f2bf(v.x) | ((u32)f2bf(v.y) << 16);
  u32 b = (u32)f2bf(v.z) | ((u32)f2bf(v.w) << 16);
  ((uint2*)out)[i] = make_uint2(a, b);
}

// ---------------------------------------------------------------------------
// convert + transpose: in [R][C] fp32 -> out [C][R] bf16 (64x64 tiles)
// ---------------------------------------------------------------------------
__global__ __launch_bounds__(256) void conv_tr(const float* __restrict__ in,
                                               u16* __restrict__ out, int R, int C) {
  __shared__ float tb[64][68];
  const int c0 = blockIdx.x * 64, r0 = blockIdx.y * 64;
  const int t = threadIdx.x;
#pragma unroll
  for (int i = 0; i < 4; ++i) {
    int idx = i * 1024 + t * 4;
    int r = idx >> 6, c = idx & 63;
    float4 v = *(const float4*)(&in[(size_t)(r0 + r) * C + c0 + c]);
    tb[r][c] = v.x; tb[r][c + 1] = v.y; tb[r][c + 2] = v.z; tb[r][c + 3] = v.w;
  }
  __syncthreads();
  const int cc = t >> 2, rr0 = (t & 3) * 16;
  u16 tmp[16];
#pragma unroll
  for (int j = 0; j < 16; ++j) tmp[j] = f2bf(tb[rr0 + j][cc]);
#pragma unroll
  for (int j = 0; j < 4; ++j) {
    u32 a = (u32)tmp[4 * j] | ((u32)tmp[4 * j + 1] << 16);
    u32 b = (u32)tmp[4 * j + 2] | ((u32)tmp[4 * j + 3] << 16);
    *(uint2*)(&out[(size_t)(c0 + cc) * R + r0 + rr0 + 4 * j]) = make_uint2(a, b);
  }
}

// ---------------------------------------------------------------------------
// shared bf16 MFMA GEMM core: C[128x128] tile, BK=64, A[M][K] row-major bf16,
// B given as BT[N][K] row-major bf16. Both row strides = 512 elems (1024 B).
// ---------------------------------------------------------------------------
template <int KTOT>
__device__ __forceinline__ void gemm_core(const u16* __restrict__ Ag,
                                          const u16* __restrict__ Bg,
                                          int m0, int n0, f32x4 (&acc)[4][4],
                                          u16* As, u16* Bs) {
  const int t = threadIdx.x;
  const int l = t & 63, w = t >> 6;
  const int wr = w >> 1, wc = w & 1;
  const int lo = l & 15, hi = l >> 4;
  const int srow_base = w * 8 + (l >> 3);
  const int scolb = (l & 7) * 16;

  for (int k0 = 0; k0 < KTOT; k0 += 64) {
    __syncthreads();
#pragma unroll
    for (int i = 0; i < 4; ++i) {
      int row = i * 32 + srow_base;
      int sw  = (row & 7) << 4;
      GLL16((const char*)Ag + (size_t)(m0 + row) * 1024 + k0 * 2 + (scolb ^ sw),
            (char*)As + row * 128 + scolb);
      GLL16((const char*)Bg + (size_t)(n0 + row) * 1024 + k0 * 2 + (scolb ^ sw),
            (char*)Bs + row * 128 + scolb);
    }
    __syncthreads();
#pragma unroll
    for (int s = 0; s < 2; ++s) {
      s16x8 af[4], bf[4];
#pragma unroll
      for (int mi = 0; mi < 4; ++mi) {
        int row = wr * 64 + mi * 16 + lo;
        af[mi] = *(const s16x8*)((const char*)As + row * 128 +
                                 ((s * 64 + hi * 16) ^ ((row & 7) << 4)));
      }
#pragma unroll
      for (int ni = 0; ni < 4; ++ni) {
        int row = wc * 64 + ni * 16 + lo;
        bf[ni] = *(const s16x8*)((const char*)Bs + row * 128 +
                                 ((s * 64 + hi * 16) ^ ((row & 7) << 4)));
      }
#pragma unroll
      for (int mi = 0; mi < 4; ++mi)
#pragma unroll
        for (int ni = 0; ni < 4; ++ni)
          acc[mi][ni] = __builtin_amdgcn_mfma_f32_16x16x32_bf16(af[mi], bf[ni],
                                                                acc[mi][ni], 0, 0, 0);
    }
  }
}

// ---------------------------------------------------------------------------
// GEMM1: qkv = x @ W_in, scatter to q/k/v [B][H][N][D] bf16.
// q pre-scaled by 0.125*log2(e) (exp2-domain softmax downstream).
// ---------------------------------------------------------------------------
__global__ __launch_bounds__(256) void gemm_qkv(const u16* __restrict__ xb,
                                                const u16* __restrict__ WinT,
                                                u16* __restrict__ qb,
                                                u16* __restrict__ kb,
                                                u16* __restrict__ vb) {
  __shared__ __align__(16) u16 As[8192];
  __shared__ __align__(16) u16 Bs[8192];
  const int m0 = blockIdx.y * 128, n0 = blockIdx.x * 128;
  f32x4 acc[4][4];
#pragma unroll
  for (int i = 0; i < 4; ++i)
#pragma unroll
    for (int j = 0; j < 4; ++j) acc[i][j] = (f32x4){0.f, 0.f, 0.f, 0.f};

  gemm_core<CH>(xb, WinT, m0, n0, acc, As, Bs);

  const int t = threadIdx.x, l = t & 63, w = t >> 6;
  const int wr = w >> 1, wc = w & 1, lo = l & 15, hi = l >> 4;
#pragma unroll
  for (int ni = 0; ni < 4; ++ni) {
    const int n = n0 + wc * 64 + ni * 16 + lo;
    const int tq = n >> 9, h = (n >> 6) & 7, d = n & 63;
    u16* dst = (tq == 0) ? qb : ((tq == 1) ? kb : vb);
    const float sc = (tq == 0) ? 0.125f * LOG2E : 1.0f;
#pragma unroll
    for (int mi = 0; mi < 4; ++mi)
#pragma unroll
      for (int r = 0; r < 4; ++r) {
        const int m = m0 + wr * 64 + mi * 16 + hi * 4 + r;
        const int b = m >> 11, ns = m & (SEQ - 1);
        dst[((size_t)((b * NH + h) * SEQ + ns)) * HD + d] = f2bf(acc[mi][ni][r] * sc);
      }
  }
}

// ---------------------------------------------------------------------------
// MFMA flash attention, swapped-operand form. Block = (b,h) x 128 q-rows,
// 8 waves x 16 q-rows. S^T = mfma(K,Q) -> q is lane-local (col); softmax
// fully in-register; O^T = mfma(V^T, P^T) keeps q lane-local for m/l/rescale.
// ---------------------------------------------------------------------------
__global__ __launch_bounds__(512) void attn(const u16* __restrict__ qg,
                                            const u16* __restrict__ kg,
                                            const u16* __restrict__ vg,
                                            u16* __restrict__ ao) {
  __shared__ __align__(16) u16 Ks[4096];   // K  [64 kv][64 d]  swizzled
  __shared__ __align__(16) u16 Vs[4096];   // VT [64 d][64 kv]  swizzled
  __shared__ __align__(16) u16 Ps[8192];   // 8 waves x [16 q][64 kv] swizzled
  const int t = threadIdx.x, l = t & 63, w = t >> 6;
  const int lo = l & 15, hi = l >> 4;
  // XCD-aware bijective swizzle: 512 blocks = 8 XCD x 64
  const int wg = blockIdx.x;
  const int L  = (wg & 7) * 64 + (wg >> 3);
  const int bh = L >> 4, qblk = L & 15;
  const int q0 = qblk * 128;
  const u16* qp = qg + (size_t)bh * SEQ * HD;
  const u16* kp = kg + (size_t)bh * SEQ * HD;
  const u16* vp = vg + (size_t)bh * SEQ * HD;

  // Q fragment (B-operand): lane holds Q[q0+w*16+lo][s*32+hi*8 ..+8]
  s16x8 qf[2];
#pragma unroll
  for (int s = 0; s < 2; ++s)
    qf[s] = *(const s16x8*)(qp + (size_t)(q0 + w * 16 + lo) * HD + s * 32 + hi * 8);

  f32x4 oacc[4];
#pragma unroll
  for (int i = 0; i < 4; ++i) oacc[i] = (f32x4){0.f, 0.f, 0.f, 0.f};
  float m_s = -1e30f, l_s = 0.f;

  u16* Pw = Ps + w * 1024;
  const int vkv = (t & 31) * 2, vd0 = (t >> 5) * 4;
  const int krow = t >> 3, kcolb = (t & 7) * 16;
  const int swl = (lo & 7) << 4;

  for (int kt = 0; kt < SEQ; kt += 64) {
    __syncthreads();
    // stage K: 512 threads x 16B async (pre-swizzled source)
    GLL16((const char*)kp + (size_t)(kt + krow) * 128 + (kcolb ^ ((krow & 7) << 4)),
          (char*)Ks + t * 16);
    // stage V transposed: VT[d][kv], each thread 2 rows x 4 d
    {
      s16x4 v0 = *(const s16x4*)(vp + (size_t)(kt + vkv) * HD + vd0);
      s16x4 v1 = *(const s16x4*)(vp + (size_t)(kt + vkv + 1) * HD + vd0);
#pragma unroll
      for (int j = 0; j < 4; ++j) {
        int d = vd0 + j;
        u32 pw = (u32)(u16)v0[j] | ((u32)(u16)v1[j] << 16);
        *(u32*)((char*)Vs + ((d * 128 + vkv * 2) ^ ((d & 7) << 4))) = pw;
      }
    }
    __syncthreads();

    // QK^T swapped: st[ct] = S^T[kv=ct*16+hi*4+r][q=lo]
    f32x4 st[4];
#pragma unroll
    for (int i = 0; i < 4; ++i) st[i] = (f32x4){0.f, 0.f, 0.f, 0.f};
    __builtin_amdgcn_s_setprio(1);
#pragma unroll
    for (int s = 0; s < 2; ++s)
#pragma unroll
      for (int ct = 0; ct < 4; ++ct) {
        int row = ct * 16 + lo;
        s16x8 kf = *(const s16x8*)((const char*)Ks + row * 128 +
                                   ((s * 64 + hi * 16) ^ ((row & 7) << 4)));
        st[ct] = __builtin_amdgcn_mfma_f32_16x16x32_bf16(kf, qf[s], st[ct], 0, 0, 0);
      }
    __builtin_amdgcn_s_setprio(0);

    // in-register online softmax for q=lo (values already in log2 domain)
    float a0 = fmaxf(fmaxf(st[0][0], st[1][0]), fmaxf(st[2][0], st[3][0]));
    float a1 = fmaxf(fmaxf(st[0][1], st[1][1]), fmaxf(st[2][1], st[3][1]));
    float a2 = fmaxf(fmaxf(st[0][2], st[1][2]), fmaxf(st[2][2], st[3][2]));
    float a3 = fmaxf(fmaxf(st[0][3], st[1][3]), fmaxf(st[2][3], st[3][3]));
    float mx = fmaxf(fmaxf(a0, a1), fmaxf(a2, a3));
    mx = fmaxf(mx, __shfl_xor(mx, 16));
    mx = fmaxf(mx, __shfl_xor(mx, 32));
    const float mn = fmaxf(m_s, mx);
    const float rs = ex2(m_s - mn);
    m_s = mn;
    float psum[4];
#pragma unroll
    for (int ct = 0; ct < 4; ++ct) {
      float p0 = ex2(st[ct][0] - mn), p1 = ex2(st[ct][1] - mn);
      float p2 = ex2(st[ct][2] - mn), p3 = ex2(st[ct][3] - mn);
      st[ct][0] = p0; st[ct][1] = p1; st[ct][2] = p2; st[ct][3] = p3;
      psum[ct] = (p0 + p1) + (p2 + p3);
    }
    float sum = (psum[0] + psum[1]) + (psum[2] + psum[3]);
    sum += __shfl_xor(sum, 16);
    sum += __shfl_xor(sum, 32);
    l_s = l_s * rs + sum;

    // P -> LDS: regs are consecutive kv -> 2 cvt_pk + 1 ds_write_b64 per ct
#pragma unroll
    for (int ct = 0; ct < 4; ++ct) {
      u32 pk0 = cvtpk(st[ct][0], st[ct][1]);
      u32 pk1 = cvtpk(st[ct][2], st[ct][3]);
      *(uint2*)((char*)Pw + ((lo * 128 + ct * 32 + hi * 8) ^ swl)) =
          make_uint2(pk0, pk1);
    }
    // rescale O (q=lo is lane-local: rs applies directly)
#pragma unroll
    for (int ct = 0; ct < 4; ++ct) {
      oacc[ct][0] *= rs; oacc[ct][1] *= rs;
      oacc[ct][2] *= rs; oacc[ct][3] *= rs;
    }

    // PV swapped: O^T[d][q] += VT[d][kv] * P^T[kv][q]
    s16x8 pf[2];
#pragma unroll
    for (int s = 0; s < 2; ++s)
      pf[s] = *(const s16x8*)((const char*)Pw + ((lo * 128 + s * 64 + hi * 16) ^ swl));
    __builtin_amdgcn_s_setprio(1);
#pragma unroll
    for (int s = 0; s < 2; ++s)
#pragma unroll
      for (int ct = 0; ct < 4; ++ct) {
        int row = ct * 16 + lo;
        s16x8 vt = *(const s16x8*)((const char*)Vs + row * 128 +
                                   ((s * 64 + hi * 16) ^ ((row & 7) << 4)));
        oacc[ct] = __builtin_amdgcn_mfma_f32_16x16x32_bf16(vt, pf[s], oacc[ct], 0, 0, 0);
      }
    __builtin_amdgcn_s_setprio(0);
  }

  // epilogue: O[q=lo][d=ct*16+hi*4+r] -> ao[b][q][h*64+d], packed u32 stores
  const int b = bh >> 3, h = bh & 7;
  const float inv = 1.0f / l_s;
  u16* aop = ao + ((size_t)(b * SEQ) + q0 + w * 16 + lo) * CH + h * HD;
#pragma unroll
  for (int ct = 0; ct < 4; ++ct) {
    u32 o0 = cvtpk(oacc[ct][0] * inv, oacc[ct][1] * inv);
    u32 o1 = cvtpk(oacc[ct][2] * inv, oacc[ct][3] * inv);
    *(uint2*)(aop + ct * 16 + hi * 4) = make_uint2(o0, o1);
  }
}

// ---------------------------------------------------------------------------
// GEMM2: out = ao @ W_out + b_out (fp32 out)
// ---------------------------------------------------------------------------
__global__ __launch_bounds__(256) void gemm_out(const u16* __restrict__ ao,
                                                const u16* __restrict__ WoutT,
                                                const float* __restrict__ bias,
                                                float* __restrict__ out) {
  __shared__ __align__(16) u16 As[8192];
  __shared__ __align__(16) u16 Bs[8192];
  const int m0 = blockIdx.y * 128, n0 = blockIdx.x * 128;
  f32x4 acc[4][4];
#pragma unroll
  for (int i = 0; i < 4; ++i)
#pragma unroll
    for (int j = 0; j < 4; ++j) acc[i][j] = (f32x4){0.f, 0.f, 0.f, 0.f};

  gemm_core<CH>(ao, WoutT, m0, n0, acc, As, Bs);

  const int t = threadIdx.x, l = t & 63, w = t >> 6;
  const int wr = w >> 1, wc = w & 1, lo = l & 15, hi = l >> 4;
#pragma unroll
  for (int ni = 0; ni < 4; ++ni) {
    const int n = n0 + wc * 64 + ni * 16 + lo;
    const float bv = bias[n];
#pragma unroll
    for (int mi = 0; mi < 4; ++mi)
#pragma unroll
      for (int r = 0; r < 4; ++r) {
        const int m = m0 + wr * 64 + mi * 16 + hi * 4 + r;
        out[(size_t)m * CH + n] = acc[mi][ni][r] + bv;
      }
  }
}

// ---------------------------------------------------------------------------
extern "C" void kernel_launch(void* const* d_in, const int* in_sizes, int n_in,
                              void* d_out, int out_size, void* d_ws, size_t ws_size,
                              hipStream_t stream) {
  const float* x    = (const float*)d_in[0];
  const float* Win  = (const float*)d_in[1];
  const float* Wout = (const float*)d_in[2];
  const float* bout = (const float*)d_in[3];
  float* out = (float*)d_out;
  char* ws = (char*)d_ws;

  const size_t MB = 1u << 20;
  u16* xb    = (u16*)(ws);             // 8 MB  [8192][512]
  u16* WinT  = (u16*)(ws + 8 * MB);    // 1.5MB [1536][512]
  u16* WoutT = (u16*)(ws + 10 * MB);   // 0.5MB [512][512]
  u16* qb    = (u16*)(ws + 12 * MB);   // 8 MB  [B][H][N][D]
  u16* kb    = (u16*)(ws + 20 * MB);
  u16* vb    = (u16*)(ws + 28 * MB);
  u16* ao    = (u16*)(ws + 36 * MB);   // 8 MB  [8192][512]

  conv_x<<<4096, 256, 0, stream>>>(x, xb, (NB * SEQ * CH) / 4);
  conv_tr<<<dim3(C3 / 64, CH / 64), 256, 0, stream>>>(Win, WinT, CH, C3);
  conv_tr<<<dim3(CH / 64, CH / 64), 256, 0, stream>>>(Wout, WoutT, CH, CH);

  gemm_qkv<<<dim3(C3 / 128, (NB * SEQ) / 128), 256, 0, stream>>>(xb, WinT, qb, kb, vb);
  attn<<<512, 512, 0, stream>>>(qb, kb, vb, ao);
  gemm_out<<<dim3(CH / 128, (NB * SEQ) / 128), 256, 0, stream>>>(ao, WoutT, bout, out);
}

// Round 4
// 109.648 us; speedup vs baseline: 6.7093x; 1.0854x over previous
//
#include <hip/hip_runtime.h>

typedef unsigned short u16;
typedef unsigned int   u32;
using s16x8 = __attribute__((ext_vector_type(8))) short;
using s16x4 = __attribute__((ext_vector_type(4))) short;
using f32x4 = __attribute__((ext_vector_type(4))) float;

#define NB   4
#define SEQ  2048
#define CH   512
#define NH   8
#define HD   64
#define C3   1536
#define LOG2E 1.44269504088896f

__device__ __forceinline__ u16 f2bf(float f) {
  u32 u = __float_as_uint(f);
  u32 r = u + 0x7fffu + ((u >> 16) & 1u);
  return (u16)(r >> 16);
}

__device__ __forceinline__ u32 cvtpk(float a, float b) {
  u32 r;
  asm("v_cvt_pk_bf16_f32 %0, %1, %2" : "=v"(r) : "v"(a), "v"(b));
  return r;
}

__device__ __forceinline__ float ex2(float x) {
#if __has_builtin(__builtin_amdgcn_exp2f)
  return __builtin_amdgcn_exp2f(x);
#else
  return exp2f(x);
#endif
}

// async global->LDS, 16B per lane. LDS dest must be wave-uniform-base + lane*16.
#define GLL16(gp, lp) __builtin_amdgcn_global_load_lds( \
    (const __attribute__((address_space(1))) u32*)(gp), \
    (__attribute__((address_space(3))) u32*)(lp), 16, 0, 0)

// ---------------------------------------------------------------------------
// convert x -> bf16 (packed)
// ---------------------------------------------------------------------------
__global__ __launch_bounds__(256) void conv_x(const float* __restrict__ in,
                                              u16* __restrict__ out, int n4) {
  int i = blockIdx.x * 256 + threadIdx.x;
  if (i >= n4) return;
  float4 v = ((const float4*)in)[i];
  u32 a = (u32)f2bf(v.x) | ((u32)f2bf(v.y) << 16);
  u32 b = (u32)f2bf(v.z) | ((u32)f2bf(v.w) << 16);
  ((uint2*)out)[i] = make_uint2(a, b);
}

// ---------------------------------------------------------------------------
// convert + transpose: in [R][C] fp32 -> out [C][R] bf16 (64x64 tiles)
// ---------------------------------------------------------------------------
__global__ __launch_bounds__(256) void conv_tr(const float* __restrict__ in,
                                               u16* __restrict__ out, int R, int C) {
  __shared__ float tb[64][68];
  const int c0 = blockIdx.x * 64, r0 = blockIdx.y * 64;
  const int t = threadIdx.x;
#pragma unroll
  for (int i = 0; i < 4; ++i) {
    int idx = i * 1024 + t * 4;
    int r = idx >> 6, c = idx & 63;
    float4 v = *(const float4*)(&in[(size_t)(r0 + r) * C + c0 + c]);
    tb[r][c] = v.x; tb[r][c + 1] = v.y; tb[r][c + 2] = v.z; tb[r][c + 3] = v.w;
  }
  __syncthreads();
  const int cc = t >> 2, rr0 = (t & 3) * 16;
  u16 tmp[16];
#pragma unroll
  for (int j = 0; j < 16; ++j) tmp[j] = f2bf(tb[rr0 + j][cc]);
#pragma unroll
  for (int j = 0; j < 4; ++j) {
    u32 a = (u32)tmp[4 * j] | ((u32)tmp[4 * j + 1] << 16);
    u32 b = (u32)tmp[4 * j + 2] | ((u32)tmp[4 * j + 3] << 16);
    *(uint2*)(&out[(size_t)(c0 + cc) * R + r0 + rr0 + 4 * j]) = make_uint2(a, b);
  }
}

// ---------------------------------------------------------------------------
// shared bf16 MFMA GEMM core: C[128x128] tile, BK=64, A[M][K] row-major bf16,
// B given as BT[N][K] row-major bf16. Both row strides = 512 elems (1024 B).
// ---------------------------------------------------------------------------
template <int KTOT>
__device__ __forceinline__ void gemm_core(const u16* __restrict__ Ag,
                                          const u16* __restrict__ Bg,
                                          int m0, int n0, f32x4 (&acc)[4][4],
                                          u16* As, u16* Bs) {
  const int t = threadIdx.x;
  const int l = t & 63, w = t >> 6;
  const int wr = w >> 1, wc = w & 1;
  const int lo = l & 15, hi = l >> 4;
  const int srow_base = w * 8 + (l >> 3);
  const int scolb = (l & 7) * 16;

  for (int k0 = 0; k0 < KTOT; k0 += 64) {
    __syncthreads();
#pragma unroll
    for (int i = 0; i < 4; ++i) {
      int row = i * 32 + srow_base;
      int sw  = (row & 7) << 4;
      GLL16((const char*)Ag + (size_t)(m0 + row) * 1024 + k0 * 2 + (scolb ^ sw),
            (char*)As + row * 128 + scolb);
      GLL16((const char*)Bg + (size_t)(n0 + row) * 1024 + k0 * 2 + (scolb ^ sw),
            (char*)Bs + row * 128 + scolb);
    }
    __syncthreads();
#pragma unroll
    for (int s = 0; s < 2; ++s) {
      s16x8 af[4], bf[4];
#pragma unroll
      for (int mi = 0; mi < 4; ++mi) {
        int row = wr * 64 + mi * 16 + lo;
        af[mi] = *(const s16x8*)((const char*)As + row * 128 +
                                 ((s * 64 + hi * 16) ^ ((row & 7) << 4)));
      }
#pragma unroll
      for (int ni = 0; ni < 4; ++ni) {
        int row = wc * 64 + ni * 16 + lo;
        bf[ni] = *(const s16x8*)((const char*)Bs + row * 128 +
                                 ((s * 64 + hi * 16) ^ ((row & 7) << 4)));
      }
#pragma unroll
      for (int mi = 0; mi < 4; ++mi)
#pragma unroll
        for (int ni = 0; ni < 4; ++ni)
          acc[mi][ni] = __builtin_amdgcn_mfma_f32_16x16x32_bf16(af[mi], bf[ni],
                                                                acc[mi][ni], 0, 0, 0);
    }
  }
}

// ---------------------------------------------------------------------------
// GEMM1: qkv = x @ W_in, scatter to q/k/v [B][H][N][D] bf16.
// q pre-scaled by 0.125*log2(e) (exp2-domain softmax downstream).
// ---------------------------------------------------------------------------
__global__ __launch_bounds__(256) void gemm_qkv(const u16* __restrict__ xb,
                                                const u16* __restrict__ WinT,
                                                u16* __restrict__ qb,
                                                u16* __restrict__ kb,
                                                u16* __restrict__ vb) {
  __shared__ __align__(16) u16 As[8192];
  __shared__ __align__(16) u16 Bs[8192];
  const int m0 = blockIdx.y * 128, n0 = blockIdx.x * 128;
  f32x4 acc[4][4];
#pragma unroll
  for (int i = 0; i < 4; ++i)
#pragma unroll
    for (int j = 0; j < 4; ++j) acc[i][j] = (f32x4){0.f, 0.f, 0.f, 0.f};

  gemm_core<CH>(xb, WinT, m0, n0, acc, As, Bs);

  const int t = threadIdx.x, l = t & 63, w = t >> 6;
  const int wr = w >> 1, wc = w & 1, lo = l & 15, hi = l >> 4;
#pragma unroll
  for (int ni = 0; ni < 4; ++ni) {
    const int n = n0 + wc * 64 + ni * 16 + lo;
    const int tq = n >> 9, h = (n >> 6) & 7, d = n & 63;
    u16* dst = (tq == 0) ? qb : ((tq == 1) ? kb : vb);
    const float sc = (tq == 0) ? 0.125f * LOG2E : 1.0f;
#pragma unroll
    for (int mi = 0; mi < 4; ++mi)
#pragma unroll
      for (int r = 0; r < 4; ++r) {
        const int m = m0 + wr * 64 + mi * 16 + hi * 4 + r;
        const int b = m >> 11, ns = m & (SEQ - 1);
        dst[((size_t)((b * NH + h) * SEQ + ns)) * HD + d] = f2bf(acc[mi][ni][r] * sc);
      }
  }
}

// ---------------------------------------------------------------------------
// MFMA flash attention, swapped-operand + double-buffered K/V pipeline.
// Block = (b,h) x 128 q-rows, 8 waves x 16 q-rows.
// Per iteration: issue next-tile loads -> compute current -> publish -> barrier.
// Single counted drain per tile (prefetch flies under compute).
// ---------------------------------------------------------------------------
__global__ __launch_bounds__(512) void attn(const u16* __restrict__ qg,
                                            const u16* __restrict__ kg,
                                            const u16* __restrict__ vg,
                                            u16* __restrict__ ao) {
  __shared__ __align__(16) u16 Ks[2][4096];  // K  [64 kv][64 d]  swizzled
  __shared__ __align__(16) u16 Vs[2][4096];  // VT [64 d][64 kv]  swizzled
  __shared__ __align__(16) u16 Ps[8192];     // 8 waves x [16 q][64 kv] swizzled
  const int t = threadIdx.x, l = t & 63, w = t >> 6;
  const int lo = l & 15, hi = l >> 4;
  // XCD-aware bijective swizzle: 512 blocks = 8 XCD x 64
  const int wg = blockIdx.x;
  const int L  = (wg & 7) * 64 + (wg >> 3);
  const int bh = L >> 4, qblk = L & 15;
  const int q0 = qblk * 128;
  const u16* qp = qg + (size_t)bh * SEQ * HD;
  const u16* kp = kg + (size_t)bh * SEQ * HD;
  const u16* vp = vg + (size_t)bh * SEQ * HD;

  // Q fragment (B-operand): lane holds Q[q0+w*16+lo][s*32+hi*8 ..+8]
  s16x8 qf[2];
#pragma unroll
  for (int s = 0; s < 2; ++s)
    qf[s] = *(const s16x8*)(qp + (size_t)(q0 + w * 16 + lo) * HD + s * 32 + hi * 8);

  f32x4 oacc[4];
#pragma unroll
  for (int i = 0; i < 4; ++i) oacc[i] = (f32x4){0.f, 0.f, 0.f, 0.f};
  float m_s = -1e30f, l_s = 0.f;

  u16* Pw = Ps + w * 1024;
  const int vkv = (t & 31) * 2, vd0 = (t >> 5) * 4;
  const int ksrc = (t >> 3) * 128 + (((t & 7) * 16) ^ (((t >> 3) & 7) << 4));
  const int swl = (lo & 7) << 4;

  // ---- prologue: stage tile 0 ----
  GLL16((const char*)kp + ksrc, (char*)&Ks[0][0] + t * 16);
  s16x4 vr0 = *(const s16x4*)(vp + (size_t)vkv * HD + vd0);
  s16x4 vr1 = *(const s16x4*)(vp + (size_t)(vkv + 1) * HD + vd0);
#pragma unroll
  for (int j = 0; j < 4; ++j) {
    int d = vd0 + j;
    u32 pw = (u32)(u16)vr0[j] | ((u32)(u16)vr1[j] << 16);
    *(u32*)((char*)&Vs[0][0] + ((d * 128 + vkv * 2) ^ ((d & 7) << 4))) = pw;
  }
  __syncthreads();

  for (int it = 0; it < 32; ++it) {
    const int cur = it & 1, nxt = cur ^ 1;
    const u16* Kc = &Ks[cur][0];
    const u16* Vc = &Vs[cur][0];
    // ---- issue next-tile loads (fly under compute) ----
    if (it < 31) {
      const size_t nb = (size_t)(it + 1) * 64;
      GLL16((const char*)(kp + nb * HD) + ksrc, (char*)&Ks[nxt][0] + t * 16);
      vr0 = *(const s16x4*)(vp + (nb + vkv) * HD + vd0);
      vr1 = *(const s16x4*)(vp + (nb + vkv + 1) * HD + vd0);
    }

    // ---- QK^T swapped: st[ct] = S^T[kv=ct*16+hi*4+r][q=lo] ----
    f32x4 st[4];
#pragma unroll
    for (int i = 0; i < 4; ++i) st[i] = (f32x4){0.f, 0.f, 0.f, 0.f};
    __builtin_amdgcn_s_setprio(1);
#pragma unroll
    for (int s = 0; s < 2; ++s)
#pragma unroll
      for (int ct = 0; ct < 4; ++ct) {
        int row = ct * 16 + lo;
        s16x8 kf = *(const s16x8*)((const char*)Kc + row * 128 +
                                   ((s * 64 + hi * 16) ^ ((row & 7) << 4)));
        st[ct] = __builtin_amdgcn_mfma_f32_16x16x32_bf16(kf, qf[s], st[ct], 0, 0, 0);
      }
    __builtin_amdgcn_s_setprio(0);

    // ---- online softmax (exp2 domain), defer-max THR=8 ----
    float a0 = fmaxf(fmaxf(st[0][0], st[1][0]), fmaxf(st[2][0], st[3][0]));
    float a1 = fmaxf(fmaxf(st[0][1], st[1][1]), fmaxf(st[2][1], st[3][1]));
    float a2 = fmaxf(fmaxf(st[0][2], st[1][2]), fmaxf(st[2][2], st[3][2]));
    float a3 = fmaxf(fmaxf(st[0][3], st[1][3]), fmaxf(st[2][3], st[3][3]));
    float mx = fmaxf(fmaxf(a0, a1), fmaxf(a2, a3));
    mx = fmaxf(mx, __shfl_xor(mx, 16));
    mx = fmaxf(mx, __shfl_xor(mx, 32));
    if (__any(mx > m_s + 8.0f)) {
      const float mn = fmaxf(m_s, mx);
      const float rs = ex2(m_s - mn);
      m_s = mn;
      l_s *= rs;
#pragma unroll
      for (int ct = 0; ct < 4; ++ct) {
        oacc[ct][0] *= rs; oacc[ct][1] *= rs;
        oacc[ct][2] *= rs; oacc[ct][3] *= rs;
      }
    }
    float psum[4];
#pragma unroll
    for (int ct = 0; ct < 4; ++ct) {
      float p0 = ex2(st[ct][0] - m_s), p1 = ex2(st[ct][1] - m_s);
      float p2 = ex2(st[ct][2] - m_s), p3 = ex2(st[ct][3] - m_s);
      st[ct][0] = p0; st[ct][1] = p1; st[ct][2] = p2; st[ct][3] = p3;
      psum[ct] = (p0 + p1) + (p2 + p3);
    }
    float sum = (psum[0] + psum[1]) + (psum[2] + psum[3]);
    sum += __shfl_xor(sum, 16);
    sum += __shfl_xor(sum, 32);
    l_s += sum;

    // ---- P -> LDS (2 cvt_pk + ds_write_b64 per ct) ----
#pragma unroll
    for (int ct = 0; ct < 4; ++ct) {
      u32 pk0 = cvtpk(st[ct][0], st[ct][1]);
      u32 pk1 = cvtpk(st[ct][2], st[ct][3]);
      *(uint2*)((char*)Pw + ((lo * 128 + ct * 32 + hi * 8) ^ swl)) =
          make_uint2(pk0, pk1);
    }

    // ---- PV swapped: O^T[d][q] += VT[d][kv] * P^T[kv][q] ----
    s16x8 pf[2];
#pragma unroll
    for (int s = 0; s < 2; ++s)
      pf[s] = *(const s16x8*)((const char*)Pw + ((lo * 128 + s * 64 + hi * 16) ^ swl));
    __builtin_amdgcn_s_setprio(1);
#pragma unroll
    for (int s = 0; s < 2; ++s)
#pragma unroll
      for (int ct = 0; ct < 4; ++ct) {
        int row = ct * 16 + lo;
        s16x8 vt = *(const s16x8*)((const char*)Vc + row * 128 +
                                   ((s * 64 + hi * 16) ^ ((row & 7) << 4)));
        oacc[ct] = __builtin_amdgcn_mfma_f32_16x16x32_bf16(vt, pf[s], oacc[ct], 0, 0, 0);
      }
    __builtin_amdgcn_s_setprio(0);

    // ---- publish next tile, single counted drain + raw barrier ----
    if (it < 31) {
#pragma unroll
      for (int j = 0; j < 4; ++j) {
        int d = vd0 + j;
        u32 pw = (u32)(u16)vr0[j] | ((u32)(u16)vr1[j] << 16);
        *(u32*)((char*)&Vs[nxt][0] + ((d * 128 + vkv * 2) ^ ((d & 7) << 4))) = pw;
      }
      asm volatile("s_waitcnt vmcnt(0) lgkmcnt(0)" ::: "memory");
      __builtin_amdgcn_s_barrier();
      __builtin_amdgcn_sched_barrier(0);
    }
  }

  // epilogue: O[q=lo][d=ct*16+hi*4+r] -> ao[b][q][h*64+d], packed u32 stores
  const int b = bh >> 3, h = bh & 7;
  const float inv = 1.0f / l_s;
  u16* aop = ao + ((size_t)(b * SEQ) + q0 + w * 16 + lo) * CH + h * HD;
#pragma unroll
  for (int ct = 0; ct < 4; ++ct) {
    u32 o0 = cvtpk(oacc[ct][0] * inv, oacc[ct][1] * inv);
    u32 o1 = cvtpk(oacc[ct][2] * inv, oacc[ct][3] * inv);
    *(uint2*)(aop + ct * 16 + hi * 4) = make_uint2(o0, o1);
  }
}

// ---------------------------------------------------------------------------
// GEMM2: out = ao @ W_out + b_out (fp32 out)
// ---------------------------------------------------------------------------
__global__ __launch_bounds__(256) void gemm_out(const u16* __restrict__ ao,
                                                const u16* __restrict__ WoutT,
                                                const float* __restrict__ bias,
                                                float* __restrict__ out) {
  __shared__ __align__(16) u16 As[8192];
  __shared__ __align__(16) u16 Bs[8192];
  const int m0 = blockIdx.y * 128, n0 = blockIdx.x * 128;
  f32x4 acc[4][4];
#pragma unroll
  for (int i = 0; i < 4; ++i)
#pragma unroll
    for (int j = 0; j < 4; ++j) acc[i][j] = (f32x4){0.f, 0.f, 0.f, 0.f};

  gemm_core<CH>(ao, WoutT, m0, n0, acc, As, Bs);

  const int t = threadIdx.x, l = t & 63, w = t >> 6;
  const int wr = w >> 1, wc = w & 1, lo = l & 15, hi = l >> 4;
#pragma unroll
  for (int ni = 0; ni < 4; ++ni) {
    const int n = n0 + wc * 64 + ni * 16 + lo;
    const float bv = bias[n];
#pragma unroll
    for (int mi = 0; mi < 4; ++mi)
#pragma unroll
      for (int r = 0; r < 4; ++r) {
        const int m = m0 + wr * 64 + mi * 16 + hi * 4 + r;
        out[(size_t)m * CH + n] = acc[mi][ni][r] + bv;
      }
  }
}

// ---------------------------------------------------------------------------
extern "C" void kernel_launch(void* const* d_in, const int* in_sizes, int n_in,
                              void* d_out, int out_size, void* d_ws, size_t ws_size,
                              hipStream_t stream) {
  const float* x    = (const float*)d_in[0];
  const float* Win  = (const float*)d_in[1];
  const float* Wout = (const float*)d_in[2];
  const float* bout = (const float*)d_in[3];
  float* out = (float*)d_out;
  char* ws = (char*)d_ws;

  const size_t MB = 1u << 20;
  u16* xb    = (u16*)(ws);             // 8 MB  [8192][512]
  u16* WinT  = (u16*)(ws + 8 * MB);    // 1.5MB [1536][512]
  u16* WoutT = (u16*)(ws + 10 * MB);   // 0.5MB [512][512]
  u16* qb    = (u16*)(ws + 12 * MB);   // 8 MB  [B][H][N][D]
  u16* kb    = (u16*)(ws + 20 * MB);
  u16* vb    = (u16*)(ws + 28 * MB);
  u16* ao    = (u16*)(ws + 36 * MB);   // 8 MB  [8192][512]

  conv_x<<<4096, 256, 0, stream>>>(x, xb, (NB * SEQ * CH) / 4);
  conv_tr<<<dim3(C3 / 64, CH / 64), 256, 0, stream>>>(Win, WinT, CH, C3);
  conv_tr<<<dim3(CH / 64, CH / 64), 256, 0, stream>>>(Wout, WoutT, CH, CH);

  gemm_qkv<<<dim3(C3 / 128, (NB * SEQ) / 128), 256, 0, stream>>>(xb, WinT, qb, kb, vb);
  attn<<<512, 512, 0, stream>>>(qb, kb, vb, ao);
  gemm_out<<<dim3(CH / 128, (NB * SEQ) / 128), 256, 0, stream>>>(ao, WoutT, bout, out);
}